// Round 4
// baseline (336.854 us; speedup 1.0000x reference)
//
#include <hip/hip_runtime.h>
#include <cstdint>

// Problem constants
#define U_UNITS 64
#define M_SLOTS 8192
#define D_DIM   64
#define SCH     32                // split-K chunks per unit (grid = U*SCH = 2048)
#define CHUNK   (M_SLOTS / SCH)   // 256 slots per chunk
#define BLK     256

// ---------------------------------------------------------------------------
// Kernel A (fused, SINGLE PASS, online softmax): per (unit, chunk) block of
// 256 slots. Per iteration all three memory streams are in flight:
//   - attentions float4 load (score dot product, 16 lanes x 4 cols per slot)
//   - memories   float4 load (independent of score -> issues concurrently)
//   - memories   float4 store (pass-through copy)
// Running (max, sum, acc) per 16-lane group, flash-style rescale. Raw scaled
// scores are staged to the weights output region; wfix_kernel turns them into
// final weights (4 MB traffic). No inter-phase barrier, no score LDS buffer.
// grid = 2048 blocks x 256 thr, __launch_bounds__(256,8) -> 8 blocks/CU.
// NOTE: sm here is group-uniform (one e per slot), reduced only across the
// 4 groups of a wave -> NO 16x over-count (unlike the two-phase version).
// ---------------------------------------------------------------------------
__global__ __launch_bounds__(BLK, 8) void fused_kernel(
    const float* __restrict__ att,    // [U][D]
    const float* __restrict__ atts,   // [U][M][D]
    const float* __restrict__ tmpr,   // [U]
    const int*   __restrict__ mask,   // [U][M] (nonzero -> dropped)
    const float* __restrict__ mem,    // [U][M][D]
    float* __restrict__ out_w,        // [U][M]  staged raw scores (wfix finalizes)
    float* __restrict__ out_m,        // [U][M][D] pass-through copy
    float* __restrict__ pmax,         // [U*SCH]
    float* __restrict__ psum,         // [U*SCH]
    float* __restrict__ pout)         // [U*SCH][D] unnormalized PV partials
{
    const int b = blockIdx.x;
    const int u = b / SCH, c = b % SCH;
    const int tid = threadIdx.x;

    __shared__ float s_att[D_DIM];
    __shared__ int   s_mask[CHUNK];
    __shared__ float s_m[4], s_s[4];
    __shared__ float s_acc[4 * D_DIM];

    if (tid < D_DIM) s_att[tid] = att[u * D_DIM + tid];
    if (tid < CHUNK / 4)
        ((int4*)s_mask)[tid] = ((const int4*)(mask + (size_t)u * M_SLOTS + c * CHUNK))[tid];
    __syncthreads();

    const int grp = tid >> 4;             // 16 groups per block, one slot each/iter
    const int cg  = (tid & 15) * 4;       // column-group start (4 floats)
    const float a0 = s_att[cg], a1 = s_att[cg + 1];
    const float a2 = s_att[cg + 2], a3 = s_att[cg + 3];
    const float invt = 1.0f / tmpr[u];

    const size_t ubase = (size_t)u * M_SLOTS * D_DIM + (size_t)c * CHUNK * D_DIM;
    const float* __restrict__ abase = atts + ubase;
    const float* __restrict__ mbase = mem + ubase;
    float* __restrict__ obase = out_m + ubase;

    float m = -1e30f, sm = 0.f;
    float acc0 = 0.f, acc1 = 0.f, acc2 = 0.f, acc3 = 0.f;

    #pragma unroll 4
    for (int k = 0; k < CHUNK / 16; ++k) {          // 16 iterations, 16 slots each
        const int sl = k * 16 + grp;
        const float4 va = *(const float4*)(abase + (size_t)sl * D_DIM + cg);
        const float4 vm = *(const float4*)(mbase + (size_t)sl * D_DIM + cg);
        *(float4*)(obase + (size_t)sl * D_DIM + cg) = vm;   // pass-through copy

        float d = va.x * a0 + va.y * a1 + va.z * a2 + va.w * a3;
        d += __shfl_xor(d, 1);
        d += __shfl_xor(d, 2);
        d += __shfl_xor(d, 4);
        d += __shfl_xor(d, 8);
        const float wv = s_mask[sl] ? -1e30f : d * invt;
        if ((tid & 15) == 0)
            out_w[(size_t)u * M_SLOTS + c * CHUNK + sl] = wv;   // staged raw score

        // online softmax update (branchless rescale; uniform within group)
        const float newm = fmaxf(m, wv);
        const float scf  = __expf(m - newm);     // 1.0 when max unchanged
        const float e    = __expf(wv - newm);
        acc0 = acc0 * scf + e * vm.x;
        acc1 = acc1 * scf + e * vm.y;
        acc2 = acc2 * scf + e * vm.z;
        acc3 = acc3 * scf + e * vm.w;
        sm   = sm * scf + e;
        m    = newm;
    }

    // ---- combine the 4 groups within each wave (xor bits 4,5) ----
    float wm = m;
    wm = fmaxf(wm, __shfl_xor(wm, 16));
    wm = fmaxf(wm, __shfl_xor(wm, 32));
    const float f = __expf(m - wm);
    float acc[4] = {acc0 * f, acc1 * f, acc2 * f, acc3 * f};
    sm *= f;
    #pragma unroll
    for (int j = 0; j < 4; ++j) {
        acc[j] += __shfl_xor(acc[j], 16);
        acc[j] += __shfl_xor(acc[j], 32);
    }
    sm += __shfl_xor(sm, 16);
    sm += __shfl_xor(sm, 32);

    // ---- combine the 4 waves via LDS ----
    const int lane = tid & 63, w = tid >> 6;
    if (lane == 0) s_m[w] = wm;
    __syncthreads();
    const float bmx = fmaxf(fmaxf(s_m[0], s_m[1]), fmaxf(s_m[2], s_m[3]));
    const float f2  = __expf(wm - bmx);
    if (lane == 0) s_s[w] = sm * f2;
    if (lane < 16) {
        #pragma unroll
        for (int j = 0; j < 4; ++j) s_acc[w * D_DIM + lane * 4 + j] = acc[j] * f2;
    }
    __syncthreads();
    if (tid < D_DIM) {
        const float s = s_acc[tid] + s_acc[D_DIM + tid]
                      + s_acc[2 * D_DIM + tid] + s_acc[3 * D_DIM + tid];
        pout[(size_t)b * D_DIM + tid] = s;
    }
    if (tid == 0) {
        pmax[b] = bmx;
        psum[b] = s_s[0] + s_s[1] + s_s[2] + s_s[3];   // no over-count here
    }
}

// ---------------------------------------------------------------------------
// Kernel B: per-unit global stats + final outputs.
// grid = U blocks x D threads.
// ---------------------------------------------------------------------------
__global__ void combine_out_kernel(
    const float* __restrict__ pmax,
    const float* __restrict__ psum,
    const float* __restrict__ pout,
    float* __restrict__ gmx,          // [U]
    float* __restrict__ ginv,         // [U]
    float* __restrict__ out_o)        // [U][D]
{
    const int u = blockIdx.x, t = threadIdx.x;
    float mx = -1e30f;
    #pragma unroll
    for (int c = 0; c < SCH; ++c) mx = fmaxf(mx, pmax[u * SCH + c]);
    float s = 0.f;
    #pragma unroll
    for (int c = 0; c < SCH; ++c) s += psum[u * SCH + c] * __expf(pmax[u * SCH + c] - mx);
    const float inv = 1.0f / s;
    float o = 0.f;
    #pragma unroll
    for (int c = 0; c < SCH; ++c)
        o += __expf(pmax[u * SCH + c] - mx) * pout[((size_t)u * SCH + c) * D_DIM + t];
    out_o[u * D_DIM + t] = o * inv;
    if (t == 0) { gmx[u] = mx; ginv[u] = inv; }
}

// ---------------------------------------------------------------------------
// Kernel C: weights finalize in place: w = exp(sc - gmx[u]) * ginv[u].
// 4 MB traffic. One float4 per thread; grid = U*M/4/BLK = 512 blocks.
// Masked slots staged sc = -1e30 -> expf underflows to exactly 0.
// ---------------------------------------------------------------------------
__global__ __launch_bounds__(BLK) void wfix_kernel(
    const float* __restrict__ gmx,
    const float* __restrict__ ginv,
    float* __restrict__ out_w)
{
    const int g = blockIdx.x * BLK + threadIdx.x;   // float4 index, U*M/4 total
    const int u = g >> 11;                          // 2048 float4 per unit
    const float a = gmx[u], gi = ginv[u];
    float4* p = reinterpret_cast<float4*>(out_w) + g;
    float4 v = *p;
    v.x = __expf(v.x - a) * gi;
    v.y = __expf(v.y - a) * gi;
    v.z = __expf(v.z - a) * gi;
    v.w = __expf(v.w - a) * gi;
    *p = v;
}

extern "C" void kernel_launch(void* const* d_in, const int* in_sizes, int n_in,
                              void* d_out, int out_size, void* d_ws, size_t ws_size,
                              hipStream_t stream)
{
    const float* att  = (const float*)d_in[0];  // attention  [64,64]
    const float* atts = (const float*)d_in[1];  // attentions [64,8192,64]
    const float* mem  = (const float*)d_in[2];  // memories   [64,8192,64]
    const float* tmpr = (const float*)d_in[3];  // tmpr       [64,1]
    const int*   mask = (const int*)d_in[4];    // mask       [64,8192]

    float* out   = (float*)d_out;
    float* out_o = out;                                   // outputs  [64,64]
    float* out_w = out + U_UNITS * D_DIM;                 // weights  [64,8192]
    float* out_m = out_w + (size_t)U_UNITS * M_SLOTS;     // memories [64,8192,64]

    float* ws    = (float*)d_ws;
    float* pmax  = ws;                                // U*SCH
    float* psum  = pmax + U_UNITS * SCH;              // U*SCH
    float* gmx   = psum + U_UNITS * SCH;              // U
    float* ginv  = gmx + U_UNITS;                     // U
    float* pout  = ginv + U_UNITS;                    // U*SCH*D

    fused_kernel<<<U_UNITS * SCH, BLK, 0, stream>>>(
        att, atts, tmpr, mask, mem, out_w, out_m, pmax, psum, pout);
    combine_out_kernel<<<U_UNITS, D_DIM, 0, stream>>>(pmax, psum, pout, gmx, ginv, out_o);
    wfix_kernel<<<(U_UNITS * M_SLOTS / 4) / BLK, BLK, 0, stream>>>(gmx, ginv, out_w);
}

// Round 5
// 328.848 us; speedup vs baseline: 1.0243x; 1.0243x over previous
//
#include <hip/hip_runtime.h>
#include <cstdint>

// Problem constants
#define U_UNITS 64
#define M_SLOTS 8192
#define D_DIM   64
#define SCH     32                // split-K chunks per unit (grid = U*SCH = 2048)
#define CHUNK   (M_SLOTS / SCH)   // 256 slots per chunk
#define BLK     256
#define SPG     4                 // slots per 16-lane group per iteration

// ---------------------------------------------------------------------------
// Kernel A (fused, single pass, online softmax, 4-slot batched iterations):
// per (unit, chunk) block of 256 slots. Each 16-lane group handles 4
// consecutive slots per iteration:
//   - 8 independent float4 loads issued back-to-back (4 attentions + 4
//     memories) -> 8 KB/wave in flight (4x the previous version's MLP)
//   - 4 dot products with 4 interleaved (pipelined) shfl_xor chains
//   - ONE online-softmax rescale per 4 slots (5 exps / 4 slots, was 2/slot)
//   - one coalesced float4 score store per group (was 4 scalar scatters)
// Outer loop = 4 fully-unrolled iterations so the compiler can hoist the
// next iteration's loads above the current compute chain.
// Raw scaled scores staged to the weights output region; wfix finalizes.
// ---------------------------------------------------------------------------
__global__ __launch_bounds__(BLK, 4) void fused_kernel(
    const float* __restrict__ att,    // [U][D]
    const float* __restrict__ atts,   // [U][M][D]
    const float* __restrict__ tmpr,   // [U]
    const int*   __restrict__ mask,   // [U][M] (nonzero -> dropped)
    const float* __restrict__ mem,    // [U][M][D]
    float* __restrict__ out_w,        // [U][M]  staged raw scores (wfix finalizes)
    float* __restrict__ out_m,        // [U][M][D] pass-through copy
    float* __restrict__ pmax,         // [U*SCH]
    float* __restrict__ psum,         // [U*SCH]
    float* __restrict__ pout)         // [U*SCH][D] unnormalized PV partials
{
    const int b = blockIdx.x;
    const int u = b / SCH, c = b % SCH;
    const int tid = threadIdx.x;

    __shared__ float s_att[D_DIM];
    __shared__ int   s_mask[CHUNK];
    __shared__ float s_m[4], s_s[4];
    __shared__ float s_acc[4 * D_DIM];

    if (tid < D_DIM) s_att[tid] = att[u * D_DIM + tid];
    if (tid < CHUNK / 4)
        ((int4*)s_mask)[tid] = ((const int4*)(mask + (size_t)u * M_SLOTS + c * CHUNK))[tid];
    __syncthreads();

    const int grp = tid >> 4;             // 16 groups; each owns 4 slots/iter
    const int r   = tid & 15;
    const int cg  = r * 4;                // column-group start (4 floats)
    const float a0 = s_att[cg], a1 = s_att[cg + 1];
    const float a2 = s_att[cg + 2], a3 = s_att[cg + 3];
    const float invt = 1.0f / tmpr[u];

    const size_t ubase = (size_t)u * M_SLOTS * D_DIM + (size_t)c * CHUNK * D_DIM;
    const float* __restrict__ abase = atts + ubase;
    const float* __restrict__ mbase = mem + ubase;
    float* __restrict__ obase = out_m + ubase;

    float m = -1e30f, sm = 0.f;
    float acc0 = 0.f, acc1 = 0.f, acc2 = 0.f, acc3 = 0.f;

    #pragma unroll
    for (int k = 0; k < CHUNK / (16 * SPG); ++k) {      // 4 iterations
        const int sl0 = k * 64 + grp * SPG;             // 4 consecutive slots

        // ---- issue all 8 loads back-to-back (independent addresses) ----
        float4 va[SPG], vm[SPG];
        #pragma unroll
        for (int i = 0; i < SPG; ++i)
            va[i] = *(const float4*)(abase + (size_t)(sl0 + i) * D_DIM + cg);
        #pragma unroll
        for (int i = 0; i < SPG; ++i)
            vm[i] = *(const float4*)(mbase + (size_t)(sl0 + i) * D_DIM + cg);

        // ---- pass-through copy ----
        #pragma unroll
        for (int i = 0; i < SPG; ++i)
            *(float4*)(obase + (size_t)(sl0 + i) * D_DIM + cg) = vm[i];

        // ---- 4 dot products, pipelined shfl chains ----
        float wv[SPG];
        #pragma unroll
        for (int i = 0; i < SPG; ++i) {
            float d = va[i].x * a0 + va[i].y * a1 + va[i].z * a2 + va[i].w * a3;
            d += __shfl_xor(d, 1);
            d += __shfl_xor(d, 2);
            d += __shfl_xor(d, 4);
            d += __shfl_xor(d, 8);
            wv[i] = s_mask[sl0 + i] ? -1e30f : d * invt;
        }

        // coalesced score stage: one float4 per group
        if (r == 0)
            *(float4*)(out_w + (size_t)u * M_SLOTS + c * CHUNK + sl0) =
                make_float4(wv[0], wv[1], wv[2], wv[3]);

        // ---- ONE online-softmax update for 4 slots ----
        const float mx4  = fmaxf(fmaxf(wv[0], wv[1]), fmaxf(wv[2], wv[3]));
        const float newm = fmaxf(m, mx4);
        const float scf  = __expf(m - newm);     // 1.0 when max unchanged
        float e[SPG];
        #pragma unroll
        for (int i = 0; i < SPG; ++i) e[i] = __expf(wv[i] - newm);
        acc0 = acc0 * scf + e[0] * vm[0].x + e[1] * vm[1].x + e[2] * vm[2].x + e[3] * vm[3].x;
        acc1 = acc1 * scf + e[0] * vm[0].y + e[1] * vm[1].y + e[2] * vm[2].y + e[3] * vm[3].y;
        acc2 = acc2 * scf + e[0] * vm[0].z + e[1] * vm[1].z + e[2] * vm[2].z + e[3] * vm[3].z;
        acc3 = acc3 * scf + e[0] * vm[0].w + e[1] * vm[1].w + e[2] * vm[2].w + e[3] * vm[3].w;
        sm   = sm * scf + (e[0] + e[1]) + (e[2] + e[3]);
        m    = newm;
    }

    // ---- combine the 4 groups within each wave (xor bits 4,5) ----
    float wm = m;
    wm = fmaxf(wm, __shfl_xor(wm, 16));
    wm = fmaxf(wm, __shfl_xor(wm, 32));
    const float f = __expf(m - wm);
    float acc[4] = {acc0 * f, acc1 * f, acc2 * f, acc3 * f};
    sm *= f;
    #pragma unroll
    for (int j = 0; j < 4; ++j) {
        acc[j] += __shfl_xor(acc[j], 16);
        acc[j] += __shfl_xor(acc[j], 32);
    }
    sm += __shfl_xor(sm, 16);
    sm += __shfl_xor(sm, 32);

    // ---- combine the 4 waves via LDS ----
    const int lane = tid & 63, w = tid >> 6;
    if (lane == 0) s_m[w] = wm;
    __syncthreads();
    const float bmx = fmaxf(fmaxf(s_m[0], s_m[1]), fmaxf(s_m[2], s_m[3]));
    const float f2  = __expf(wm - bmx);
    if (lane == 0) s_s[w] = sm * f2;
    if (lane < 16) {
        #pragma unroll
        for (int j = 0; j < 4; ++j) s_acc[w * D_DIM + lane * 4 + j] = acc[j] * f2;
    }
    __syncthreads();
    if (tid < D_DIM) {
        const float s = s_acc[tid] + s_acc[D_DIM + tid]
                      + s_acc[2 * D_DIM + tid] + s_acc[3 * D_DIM + tid];
        pout[(size_t)b * D_DIM + tid] = s;
    }
    if (tid == 0) {
        pmax[b] = bmx;
        psum[b] = s_s[0] + s_s[1] + s_s[2] + s_s[3];   // group-uniform sm: no over-count
    }
}

// ---------------------------------------------------------------------------
// Kernel B: per-unit global stats + final outputs.
// grid = U blocks x D threads.
// ---------------------------------------------------------------------------
__global__ void combine_out_kernel(
    const float* __restrict__ pmax,
    const float* __restrict__ psum,
    const float* __restrict__ pout,
    float* __restrict__ gmx,          // [U]
    float* __restrict__ ginv,         // [U]
    float* __restrict__ out_o)        // [U][D]
{
    const int u = blockIdx.x, t = threadIdx.x;
    float mx = -1e30f;
    #pragma unroll
    for (int c = 0; c < SCH; ++c) mx = fmaxf(mx, pmax[u * SCH + c]);
    float s = 0.f;
    #pragma unroll
    for (int c = 0; c < SCH; ++c) s += psum[u * SCH + c] * __expf(pmax[u * SCH + c] - mx);
    const float inv = 1.0f / s;
    float o = 0.f;
    #pragma unroll
    for (int c = 0; c < SCH; ++c)
        o += __expf(pmax[u * SCH + c] - mx) * pout[((size_t)u * SCH + c) * D_DIM + t];
    out_o[u * D_DIM + t] = o * inv;
    if (t == 0) { gmx[u] = mx; ginv[u] = inv; }
}

// ---------------------------------------------------------------------------
// Kernel C: weights finalize in place: w = exp(sc - gmx[u]) * ginv[u].
// 4 MB traffic. One float4 per thread; grid = U*M/4/BLK = 512 blocks.
// Masked slots staged sc = -1e30 -> expf underflows to exactly 0.
// ---------------------------------------------------------------------------
__global__ __launch_bounds__(BLK) void wfix_kernel(
    const float* __restrict__ gmx,
    const float* __restrict__ ginv,
    float* __restrict__ out_w)
{
    const int g = blockIdx.x * BLK + threadIdx.x;   // float4 index, U*M/4 total
    const int u = g >> 11;                          // 2048 float4 per unit
    const float a = gmx[u], gi = ginv[u];
    float4* p = reinterpret_cast<float4*>(out_w) + g;
    float4 v = *p;
    v.x = __expf(v.x - a) * gi;
    v.y = __expf(v.y - a) * gi;
    v.z = __expf(v.z - a) * gi;
    v.w = __expf(v.w - a) * gi;
    *p = v;
}

extern "C" void kernel_launch(void* const* d_in, const int* in_sizes, int n_in,
                              void* d_out, int out_size, void* d_ws, size_t ws_size,
                              hipStream_t stream)
{
    const float* att  = (const float*)d_in[0];  // attention  [64,64]
    const float* atts = (const float*)d_in[1];  // attentions [64,8192,64]
    const float* mem  = (const float*)d_in[2];  // memories   [64,8192,64]
    const float* tmpr = (const float*)d_in[3];  // tmpr       [64,1]
    const int*   mask = (const int*)d_in[4];    // mask       [64,8192]

    float* out   = (float*)d_out;
    float* out_o = out;                                   // outputs  [64,64]
    float* out_w = out + U_UNITS * D_DIM;                 // weights  [64,8192]
    float* out_m = out_w + (size_t)U_UNITS * M_SLOTS;     // memories [64,8192,64]

    float* ws    = (float*)d_ws;
    float* pmax  = ws;                                // U*SCH
    float* psum  = pmax + U_UNITS * SCH;              // U*SCH
    float* gmx   = psum + U_UNITS * SCH;              // U
    float* ginv  = gmx + U_UNITS;                     // U
    float* pout  = ginv + U_UNITS;                    // U*SCH*D

    fused_kernel<<<U_UNITS * SCH, BLK, 0, stream>>>(
        att, atts, tmpr, mask, mem, out_w, out_m, pmax, psum, pout);
    combine_out_kernel<<<U_UNITS, D_DIM, 0, stream>>>(pmax, psum, pout, gmx, ginv, out_o);
    wfix_kernel<<<(U_UNITS * M_SLOTS / 4) / BLK, BLK, 0, stream>>>(gmx, ginv, out_w);
}